// Round 4
// baseline (627.750 us; speedup 1.0000x reference)
//
#include <hip/hip_runtime.h>
#include <math.h>

#define N_NODES 32768
#define F 128
#define KD 64
#define UNITS 8                 // node-pairs per attn block (software pipeline)

typedef short  s8v  __attribute__((ext_vector_type(8)));   // 8 x bf16 (bit pattern)
typedef float  f4v  __attribute__((ext_vector_type(4)));   // MFMA accumulator
typedef unsigned short u16;

__device__ __forceinline__ float ssp(float a) {
    return fmaxf(a, 0.0f) + log1pf(expf(-fabsf(a))) - 0.69314718055994531f;
}
__device__ __forceinline__ u16 f2b(float f) {               // fp32 -> bf16 RNE
    unsigned int u = __builtin_bit_cast(unsigned int, f);
    u += 0x7fffu + ((u >> 16) & 1u);
    return (u16)(u >> 16);
}
__device__ __forceinline__ float b2f(u16 h) {
    unsigned int u = ((unsigned int)h) << 16;
    return __builtin_bit_cast(float, u);
}

// ---------------------------------------------------------------------------
// MFMA GEMM core (64-row tile): A in LDS [64][136] bf16, 128 cols, K=128.
// Wave w owns rows w*16..w*16+15. C/D: col=lane&15, row=(lane>>4)*4+reg.
// ---------------------------------------------------------------------------
__device__ __forceinline__ void mfma_gemm64(const u16* A_b, const u16* Wg,
                                            int w, int m, int q, f4v acc[8])
{
    #pragma unroll
    for (int ct = 0; ct < 8; ++ct) acc[ct] = (f4v){0.f, 0.f, 0.f, 0.f};
    #pragma unroll
    for (int ks = 0; ks < 4; ++ks) {
        s8v a = *(const s8v*)&A_b[(w * 16 + m) * 136 + ks * 32 + q * 8];
        #pragma unroll
        for (int ct = 0; ct < 8; ++ct) {
            s8v b = *(const s8v*)&Wg[(ct * 16 + m) * 128 + ks * 32 + q * 8];
            acc[ct] = __builtin_amdgcn_mfma_f32_16x16x32_bf16(a, b, acc[ct], 0, 0, 0);
        }
    }
}

// ---------------------------------------------------------------------------
// MFMA GEMM core (32-row tile, quadrant decomposition): A in LDS [32][136].
// Wave w = (rh = w&1, ch = w>>1): rows rh*16..+15, cols ch*64 + ct*16 + m.
// ---------------------------------------------------------------------------
__device__ __forceinline__ void mfma_gemm32(const u16* A_b, const u16* Wg,
                                            int rh, int cbase, int m, int q, f4v acc[4])
{
    #pragma unroll
    for (int ct = 0; ct < 4; ++ct) acc[ct] = (f4v){0.f, 0.f, 0.f, 0.f};
    #pragma unroll
    for (int ks = 0; ks < 4; ++ks) {
        s8v a = *(const s8v*)&A_b[(rh * 16 + m) * 136 + ks * 32 + q * 8];
        #pragma unroll
        for (int ct = 0; ct < 4; ++ct) {
            s8v b = *(const s8v*)&Wg[(cbase + ct * 16 + m) * 128 + ks * 32 + q * 8];
            acc[ct] = __builtin_amdgcn_mfma_f32_16x16x32_bf16(a, b, acc[ct], 0, 0, 0);
        }
    }
}

__device__ __forceinline__ void writeA32(u16* A_b, int rh, int cbase, int q, int m,
                                         const float v[4][4])
{
    #pragma unroll
    for (int ct = 0; ct < 4; ++ct) {
        int c = cbase + ct * 16 + m;
        #pragma unroll
        for (int reg = 0; reg < 4; ++reg)
            A_b[(rh * 16 + q * 4 + reg) * 136 + c] = f2b(v[ct][reg]);
    }
}

// ---------------------------------------------------------------------------
// prep: fp32 -> bf16 for weights + k2f.
// ---------------------------------------------------------------------------
__global__ __launch_bounds__(256)
void prep_kernel(const float* __restrict__ wi, const float* __restrict__ wj,
                 const float* __restrict__ rw1, const float* __restrict__ rw2,
                 const float* __restrict__ wd, const float* __restrict__ k2f,
                 u16* __restrict__ WB, u16* __restrict__ K2FB)
{
    int b = blockIdx.x, t = threadIdx.x;
    const float* src; u16* dst; int off;
    if (b < 112) {
        int seg = b >> 4; off = (b & 15) * 1024 + t * 4;
        const float* srcs[7] = {wi, wj, rw1, rw2, rw1 + 16384, rw2 + 16384, wd};
        src = srcs[seg]; dst = WB + seg * 16384;
    } else {
        off = (b - 112) * 1024 + t * 4;
        src = k2f; dst = K2FB;
    }
    float4 v = *(const float4*)(src + off);
    ushort4 h; h.x = f2b(v.x); h.y = f2b(v.y); h.z = f2b(v.z); h.w = f2b(v.w);
    *(ushort4*)(dst + off) = h;
}

// ---------------------------------------------------------------------------
// in (round-2 proven version): SPLIT into 2 block types, grid 1024.
//   bt=0: xi = ssp(x)@wi^T+bi ; bt=1: xv = ssp(x)@wj^T+bj (bf16)
// ---------------------------------------------------------------------------
__global__ __launch_bounds__(256, 4)
void in_kernel(const float* __restrict__ x, const u16* __restrict__ WB,
               const float* __restrict__ bi, const float* __restrict__ bj,
               float* __restrict__ xi_out, u16* __restrict__ xv_out)
{
    __shared__ u16 A_b[64 * 136];
    const int t = threadIdx.x;
    const int bt = blockIdx.x >> 9;                 // 0: wi/xi, 1: wj/xv
    const int row0 = (blockIdx.x & 511) * 64;
    const int w = t >> 6, lane = t & 63, m = lane & 15, q = lane >> 4;

    {   // stage A = bf16(ssp(x))
        const float4* xg = (const float4*)(x + (size_t)row0 * F);
        #pragma unroll
        for (int i = 0; i < 8; ++i) {
            int idx = i * 256 + t, r = idx >> 5, seg = idx & 31;
            float4 v = xg[idx];
            ushort4 h;
            h.x = f2b(ssp(v.x)); h.y = f2b(ssp(v.y));
            h.z = f2b(ssp(v.z)); h.w = f2b(ssp(v.w));
            *(ushort4*)&A_b[r * 136 + seg * 4] = h;
        }
    }
    __syncthreads();

    f4v acc[8];
    if (bt == 0) {
        mfma_gemm64(A_b, WB + 0 * 16384, w, m, q, acc);     // wi
        #pragma unroll
        for (int ct = 0; ct < 8; ++ct) {
            int c = ct * 16 + m; float bv = bi[c];
            #pragma unroll
            for (int reg = 0; reg < 4; ++reg) {
                int r = row0 + w * 16 + q * 4 + reg;
                xi_out[(size_t)r * F + c] = acc[ct][reg] + bv;
            }
        }
    } else {
        mfma_gemm64(A_b, WB + 1 * 16384, w, m, q, acc);     // wj
        __syncthreads();   // all A_b reads done; reuse A_b for xv staging
        #pragma unroll
        for (int ct = 0; ct < 8; ++ct) {
            int c = ct * 16 + m; float bv = bj[c];
            #pragma unroll
            for (int reg = 0; reg < 4; ++reg)
                A_b[(w * 16 + q * 4 + reg) * 136 + c] = f2b(acc[ct][reg] + bv);
        }
        __syncthreads();
        // coalesced bf16 stores: 64 rows x 128 cols
        u16* dst = xv_out + (size_t)row0 * F;
        #pragma unroll
        for (int i = 0; i < 8; ++i) {
            int idx = i * 256 + t, r = idx >> 5, seg = idx & 31;
            *(ushort4*)&dst[r * F + seg * 4] = *(const ushort4*)&A_b[r * 136 + seg * 4];
        }
    }
}

// ---------------------------------------------------------------------------
// attn v4: round-0 proven per-unit implementation, but each block runs
// UNITS=8 consecutive 2-node units with a register-only software pipeline:
// unit t+1's global data (idx->gather, rbf, xi) is prefetched during unit
// t's logits/softmax/combine phases (~2k cycles — covers L2 idx + gather
// and the rbf HBM latency). LDS stays single-buffered: prefetched regs are
// consumed before their next overwrite (af in g-GEMM, xv_r in multiply,
// xif at loop top). Reg budget at (256,4) = 128/wave (unified arch+acc):
// ~37 prefetch + 32 acc + ~35 working ~= 105 -> no spill expected
// (R3's spill was xv_r[8]+acc live simultaneously; here xv_r[4] only).
// ---------------------------------------------------------------------------
__device__ __forceinline__ void attn_prefetch(
    const float* __restrict__ xi_in, const u16* __restrict__ xvb,
    const float* __restrict__ rbf, const int* __restrict__ idx_j,
    size_t e0, int n0, int t, int w, int m, int q, int e_my, int coff,
    s8v xv_r[4], float4 af[4], float4& xif)
{
    const int jj = idx_j[e0 + e_my];
    const u16* xvp = xvb + (size_t)jj * F + coff;
    #pragma unroll
    for (int i = 0; i < 4; ++i) xv_r[i] = *(const s8v*)(xvp + i * 8);
    const float* arow = rbf + (e0 + (size_t)(w * 16 + m)) * KD;
    #pragma unroll
    for (int ks = 0; ks < 2; ++ks) {
        af[ks * 2]     = *(const float4*)(arow + ks * 32 + q * 8);
        af[ks * 2 + 1] = *(const float4*)(arow + ks * 32 + q * 8 + 4);
    }
    if (t < 64) xif = ((const float4*)(xi_in + (size_t)n0 * F))[t];
}

__global__ __launch_bounds__(256, 4)
void attn_kernel(const float* __restrict__ xi_in, const u16* __restrict__ xvb,
                 const float* __restrict__ rbf, const int* __restrict__ idx_j,
                 const u16* __restrict__ k2fb, float* __restrict__ m_out)
{
    __shared__ u16   xj_s[64 * 136];     // 17408 B
    __shared__ float xi_s[2 * 128];
    __shared__ float red_s[2][2][32];
    __shared__ float att_s[2 * 32];

    const int t = threadIdx.x;
    const int w = t >> 6, lane = t & 63, m = lane & 15, q = lane >> 4;
    const int e_my = t >> 2, coff = (t & 3) * 32;

    s8v    xv_r[4];
    float4 af[4];
    float4 xif;

    // prologue: prefetch unit 0
    attn_prefetch(xi_in, xvb, rbf, idx_j,
                  (size_t)blockIdx.x * (UNITS * 64), blockIdx.x * (UNITS * 2),
                  t, w, m, q, e_my, coff, xv_r, af, xif);

    #pragma unroll 1
    for (int u = 0; u < UNITS; ++u) {
        const size_t e0 = (size_t)blockIdx.x * (UNITS * 64) + (size_t)u * 64;
        const int n0 = blockIdx.x * (UNITS * 2) + u * 2;

        // xi regs -> wave LDS (consumed by logits after the next barrier)
        if (t < 64) ((float4*)xi_s)[t] = xif;

        // ---- g-GEMM: 64 edges x 128 cols x K=64, A from prefetched af regs
        f4v acc[8];
        #pragma unroll
        for (int ct = 0; ct < 8; ++ct) acc[ct] = (f4v){0.f, 0.f, 0.f, 0.f};
        #pragma unroll
        for (int ks = 0; ks < 2; ++ks) {
            float4 a0 = af[ks * 2], a1 = af[ks * 2 + 1];
            s8v a;
            a[0] = (short)f2b(a0.x); a[1] = (short)f2b(a0.y);
            a[2] = (short)f2b(a0.z); a[3] = (short)f2b(a0.w);
            a[4] = (short)f2b(a1.x); a[5] = (short)f2b(a1.y);
            a[6] = (short)f2b(a1.z); a[7] = (short)f2b(a1.w);
            #pragma unroll
            for (int ct = 0; ct < 8; ++ct) {
                s8v b = *(const s8v*)&k2fb[(ct * 16 + m) * KD + ks * 32 + q * 8];
                acc[ct] = __builtin_amdgcn_mfma_f32_16x16x32_bf16(a, b, acc[ct], 0, 0, 0);
            }
        }
        // g -> xj_s (bf16, C-layout scatter)
        #pragma unroll
        for (int ct = 0; ct < 8; ++ct) {
            int c = ct * 16 + m;
            #pragma unroll
            for (int reg = 0; reg < 4; ++reg)
                xj_s[(w * 16 + q * 4 + reg) * 136 + c] = f2b(acc[ct][reg]);
        }
        __syncthreads();

        // ---- xj *= xv (prefetched): 4 threads/edge, b128 RMW
        #pragma unroll
        for (int i = 0; i < 4; ++i) {
            u16* p = &xj_s[e_my * 136 + coff + i * 8];
            s8v g8 = *(const s8v*)p;
            s8v r;
            #pragma unroll
            for (int k = 0; k < 8; ++k)
                r[k] = (short)f2b(b2f((u16)g8[k]) * b2f((u16)xv_r[i][k]));
            *(s8v*)p = r;
        }
        __syncthreads();

        // ---- PREFETCH unit u+1 (regs free: af, xv_r, xif all consumed).
        // Runs concurrently with logits/softmax/combine below.
        if (u + 1 < UNITS)
            attn_prefetch(xi_in, xvb, rbf, idx_j, e0 + 64, n0 + 2,
                          t, w, m, q, e_my, coff, xv_r, af, xif);

        // ---- logits: all 256 threads; t = (nn, part, mm)
        {
            const int nn = t >> 7, part = (t >> 5) & 3, mm = t & 31;
            float s = 0.f;
            #pragma unroll
            for (int fo = 0; fo < 32; ++fo) {
                int f = part * 32 + fo;
                s = fmaf(xi_s[nn * 128 + f],
                         b2f(xj_s[(nn * 32 + (f >> 2)) * 136 + (f & 3) * 32 + mm]), s);
            }
            s += __shfl_xor(s, 32);          // combine part pairs within wave
            if (lane < 32) red_s[nn][w & 1][mm] = s;
        }
        __syncthreads();
        if (t < 64) {
            const int nn = t >> 5, mm = t & 31;
            float s = red_s[nn][0][mm] + red_s[nn][1][mm];
            float mx = s;
            #pragma unroll
            for (int o = 16; o; o >>= 1) mx = fmaxf(mx, __shfl_xor(mx, o));
            float ex = expf(s - mx);
            float sum = ex;
            #pragma unroll
            for (int o = 16; o; o >>= 1) sum += __shfl_xor(sum, o);
            att_s[nn * 32 + mm] = ex / sum;
        }
        __syncthreads();

        // ---- m[n][f] = xi + sum_m att*xj[32n+m][f] ; coalesced fp32 store
        {
            const int nn = t >> 7, f = t & 127;
            float v = xi_s[nn * 128 + f];
            #pragma unroll
            for (int mm = 0; mm < 32; ++mm)
                v = fmaf(att_s[nn * 32 + mm], b2f(xj_s[(nn * 32 + mm) * 136 + f]), v);
            m_out[(size_t)(n0 + nn) * F + f] = v;
        }
        __syncthreads();   // xj_s/xi_s/att_s reused by next unit
    }
}

// ---------------------------------------------------------------------------
// tail (round-2 proven version): 32-row tiles, quadrant wave decomposition,
// grid 1024 = 4 blocks/CU.
// ---------------------------------------------------------------------------
__global__ __launch_bounds__(256, 4)
void tail_kernel(const float* __restrict__ m_in, const float* __restrict__ x,
                 const float* __restrict__ u, const u16* __restrict__ WB,
                 const float* __restrict__ rb1, const float* __restrict__ rb2,
                 const float* __restrict__ bd, float* __restrict__ out)
{
    __shared__ u16 A_b[32 * 136];
    const int t = threadIdx.x, row0 = blockIdx.x * 32;
    const int w = t >> 6, lane = t & 63, m = lane & 15, q = lane >> 4;
    const int rh = w & 1, cbase = (w >> 1) * 64;
    const int rbase = row0 + rh * 16 + q * 4;

    float cur[4][4], tmp[4][4];
    #pragma unroll
    for (int ct = 0; ct < 4; ++ct) {
        int c = cbase + ct * 16 + m;
        #pragma unroll
        for (int reg = 0; reg < 4; ++reg)
            cur[ct][reg] = m_in[(size_t)(rbase + reg) * F + c];
    }

    f4v acc[4];
    #pragma unroll 1
    for (int r = 0; r < 2; ++r) {
        #pragma unroll
        for (int ct = 0; ct < 4; ++ct)
            #pragma unroll
            for (int reg = 0; reg < 4; ++reg) tmp[ct][reg] = ssp(cur[ct][reg]);
        writeA32(A_b, rh, cbase, q, m, tmp);
        __syncthreads();
        mfma_gemm32(A_b, WB + (2 + 2 * r) * 16384, rh, cbase, m, q, acc);   // rw1_r
        __syncthreads();
        #pragma unroll
        for (int ct = 0; ct < 4; ++ct) {
            float bv = rb1[r * F + cbase + ct * 16 + m];
            #pragma unroll
            for (int reg = 0; reg < 4; ++reg) tmp[ct][reg] = acc[ct][reg] + bv;
        }
        writeA32(A_b, rh, cbase, q, m, tmp);
        __syncthreads();
        mfma_gemm32(A_b, WB + (3 + 2 * r) * 16384, rh, cbase, m, q, acc);   // rw2_r
        #pragma unroll
        for (int ct = 0; ct < 4; ++ct) {
            float bv = rb2[r * F + cbase + ct * 16 + m];
            #pragma unroll
            for (int reg = 0; reg < 4; ++reg) cur[ct][reg] += acc[ct][reg] + bv;
        }
        __syncthreads();
    }

    #pragma unroll
    for (int ct = 0; ct < 4; ++ct)
        #pragma unroll
        for (int reg = 0; reg < 4; ++reg) tmp[ct][reg] = ssp(cur[ct][reg]);
    writeA32(A_b, rh, cbase, q, m, tmp);
    __syncthreads();
    mfma_gemm32(A_b, WB + 6 * 16384, rh, cbase, m, q, acc);                 // wd
    #pragma unroll
    for (int ct = 0; ct < 4; ++ct) {
        int c = cbase + ct * 16 + m;
        float uv = u[c], bv = bd[c];
        #pragma unroll
        for (int reg = 0; reg < 4; ++reg) {
            size_t r = (size_t)(rbase + reg) * F + c;
            out[r] = fmaf(uv, x[r], acc[ct][reg] + bv);
        }
    }
}

// ---------------------------------------------------------------------------
extern "C" void kernel_launch(void* const* d_in, const int* in_sizes, int n_in,
                              void* d_out, int out_size, void* d_ws, size_t ws_size,
                              hipStream_t stream)
{
    const float* x     = (const float*)d_in[0];
    const float* rbf   = (const float*)d_in[1];
    const int*   idx_j = (const int*)d_in[3];   // idx_i (d_in[2]) unused by ref
    const float* k2f_w = (const float*)d_in[4];
    const float* wi    = (const float*)d_in[5];
    const float* bi    = (const float*)d_in[6];
    const float* wj    = (const float*)d_in[7];
    const float* bj    = (const float*)d_in[8];
    const float* rw1   = (const float*)d_in[9];
    const float* rb1   = (const float*)d_in[10];
    const float* rw2   = (const float*)d_in[11];
    const float* rb2   = (const float*)d_in[12];
    const float* wd    = (const float*)d_in[13];
    const float* bd    = (const float*)d_in[14];
    const float* u     = (const float*)d_in[15];
    float* out = (float*)d_out;

    const size_t NF = (size_t)N_NODES * F;
    float* B0   = (float*)d_ws;          // xi, then m (attn writes in place)
    u16*   XVB  = (u16*)(B0 + NF);       // xv bf16
    u16*   WB   = XVB + NF;              // 7 x [128][128] bf16 weights
    u16*   K2FB = WB + 7 * 16384;        // [128][64] bf16

    hipLaunchKernelGGL(prep_kernel, dim3(120), dim3(256), 0, stream,
                       wi, wj, rw1, rw2, wd, k2f_w, WB, K2FB);

    hipLaunchKernelGGL(in_kernel, dim3(1024), dim3(256), 0, stream,
                       x, WB, bi, bj, B0, XVB);

    hipLaunchKernelGGL(attn_kernel, dim3(N_NODES / (2 * UNITS)), dim3(256), 0, stream,
                       B0, XVB, rbf, idx_j, K2FB, B0);

    hipLaunchKernelGGL(tail_kernel, dim3(1024), dim3(256), 0, stream,
                       B0, x, u, WB, rb1, rb2, bd, out);
}

// Round 5
// 565.631 us; speedup vs baseline: 1.1098x; 1.1098x over previous
//
#include <hip/hip_runtime.h>
#include <math.h>

#define N_NODES 32768
#define F 128
#define KD 64

typedef short  s8v  __attribute__((ext_vector_type(8)));   // 8 x bf16 (bit pattern)
typedef float  f4v  __attribute__((ext_vector_type(4)));   // MFMA accumulator
typedef unsigned short u16;

__device__ __forceinline__ float ssp(float a) {
    return fmaxf(a, 0.0f) + log1pf(expf(-fabsf(a))) - 0.69314718055994531f;
}
__device__ __forceinline__ u16 f2b(float f) {               // fp32 -> bf16 RNE
    unsigned int u = __builtin_bit_cast(unsigned int, f);
    u += 0x7fffu + ((u >> 16) & 1u);
    return (u16)(u >> 16);
}
__device__ __forceinline__ float b2f(u16 h) {
    unsigned int u = ((unsigned int)h) << 16;
    return __builtin_bit_cast(float, u);
}

// Wave-level LDS fence (same-wave write->read ordering, no __syncthreads).
__device__ __forceinline__ void wfence() {
    asm volatile("s_waitcnt lgkmcnt(0)" ::: "memory");
    __builtin_amdgcn_wave_barrier();
    __builtin_amdgcn_sched_barrier(0);
}

// ---------------------------------------------------------------------------
// MFMA GEMM core (64-row tile): A in LDS [64][136] bf16, 128 cols, K=128.
// Wave w owns rows w*16..w*16+15. C/D: col=lane&15, row=(lane>>4)*4+reg.
// ---------------------------------------------------------------------------
__device__ __forceinline__ void mfma_gemm64(const u16* A_b, const u16* Wg,
                                            int w, int m, int q, f4v acc[8])
{
    #pragma unroll
    for (int ct = 0; ct < 8; ++ct) acc[ct] = (f4v){0.f, 0.f, 0.f, 0.f};
    #pragma unroll
    for (int ks = 0; ks < 4; ++ks) {
        s8v a = *(const s8v*)&A_b[(w * 16 + m) * 136 + ks * 32 + q * 8];
        #pragma unroll
        for (int ct = 0; ct < 8; ++ct) {
            s8v b = *(const s8v*)&Wg[(ct * 16 + m) * 128 + ks * 32 + q * 8];
            acc[ct] = __builtin_amdgcn_mfma_f32_16x16x32_bf16(a, b, acc[ct], 0, 0, 0);
        }
    }
}

// ---------------------------------------------------------------------------
// MFMA GEMM core (32-row tile, quadrant decomposition): A in LDS [32][136].
// ---------------------------------------------------------------------------
__device__ __forceinline__ void mfma_gemm32(const u16* A_b, const u16* Wg,
                                            int rh, int cbase, int m, int q, f4v acc[4])
{
    #pragma unroll
    for (int ct = 0; ct < 4; ++ct) acc[ct] = (f4v){0.f, 0.f, 0.f, 0.f};
    #pragma unroll
    for (int ks = 0; ks < 4; ++ks) {
        s8v a = *(const s8v*)&A_b[(rh * 16 + m) * 136 + ks * 32 + q * 8];
        #pragma unroll
        for (int ct = 0; ct < 4; ++ct) {
            s8v b = *(const s8v*)&Wg[(cbase + ct * 16 + m) * 128 + ks * 32 + q * 8];
            acc[ct] = __builtin_amdgcn_mfma_f32_16x16x32_bf16(a, b, acc[ct], 0, 0, 0);
        }
    }
}

__device__ __forceinline__ void writeA32(u16* A_b, int rh, int cbase, int q, int m,
                                         const float v[4][4])
{
    #pragma unroll
    for (int ct = 0; ct < 4; ++ct) {
        int c = cbase + ct * 16 + m;
        #pragma unroll
        for (int reg = 0; reg < 4; ++reg)
            A_b[(rh * 16 + q * 4 + reg) * 136 + c] = f2b(v[ct][reg]);
    }
}

// ---------------------------------------------------------------------------
// prep: fp32 -> bf16 for weights + k2f.
// ---------------------------------------------------------------------------
__global__ __launch_bounds__(256)
void prep_kernel(const float* __restrict__ wi, const float* __restrict__ wj,
                 const float* __restrict__ rw1, const float* __restrict__ rw2,
                 const float* __restrict__ wd, const float* __restrict__ k2f,
                 u16* __restrict__ WB, u16* __restrict__ K2FB)
{
    int b = blockIdx.x, t = threadIdx.x;
    const float* src; u16* dst; int off;
    if (b < 112) {
        int seg = b >> 4; off = (b & 15) * 1024 + t * 4;
        const float* srcs[7] = {wi, wj, rw1, rw2, rw1 + 16384, rw2 + 16384, wd};
        src = srcs[seg]; dst = WB + seg * 16384;
    } else {
        off = (b - 112) * 1024 + t * 4;
        src = k2f; dst = K2FB;
    }
    float4 v = *(const float4*)(src + off);
    ushort4 h; h.x = f2b(v.x); h.y = f2b(v.y); h.z = f2b(v.z); h.w = f2b(v.w);
    *(ushort4*)(dst + off) = h;
}

// ---------------------------------------------------------------------------
// in (round-2 proven version): SPLIT into 2 block types, grid 1024.
// ---------------------------------------------------------------------------
__global__ __launch_bounds__(256, 4)
void in_kernel(const float* __restrict__ x, const u16* __restrict__ WB,
               const float* __restrict__ bi, const float* __restrict__ bj,
               float* __restrict__ xi_out, u16* __restrict__ xv_out)
{
    __shared__ u16 A_b[64 * 136];
    const int t = threadIdx.x;
    const int bt = blockIdx.x >> 9;                 // 0: wi/xi, 1: wj/xv
    const int row0 = (blockIdx.x & 511) * 64;
    const int w = t >> 6, lane = t & 63, m = lane & 15, q = lane >> 4;

    {   // stage A = bf16(ssp(x))
        const float4* xg = (const float4*)(x + (size_t)row0 * F);
        #pragma unroll
        for (int i = 0; i < 8; ++i) {
            int idx = i * 256 + t, r = idx >> 5, seg = idx & 31;
            float4 v = xg[idx];
            ushort4 h;
            h.x = f2b(ssp(v.x)); h.y = f2b(ssp(v.y));
            h.z = f2b(ssp(v.z)); h.w = f2b(ssp(v.w));
            *(ushort4*)&A_b[r * 136 + seg * 4] = h;
        }
    }
    __syncthreads();

    f4v acc[8];
    if (bt == 0) {
        mfma_gemm64(A_b, WB + 0 * 16384, w, m, q, acc);     // wi
        #pragma unroll
        for (int ct = 0; ct < 8; ++ct) {
            int c = ct * 16 + m; float bv = bi[c];
            #pragma unroll
            for (int reg = 0; reg < 4; ++reg) {
                int r = row0 + w * 16 + q * 4 + reg;
                xi_out[(size_t)r * F + c] = acc[ct][reg] + bv;
            }
        }
    } else {
        mfma_gemm64(A_b, WB + 1 * 16384, w, m, q, acc);     // wj
        __syncthreads();   // all A_b reads done; reuse A_b for xv staging
        #pragma unroll
        for (int ct = 0; ct < 8; ++ct) {
            int c = ct * 16 + m; float bv = bj[c];
            #pragma unroll
            for (int reg = 0; reg < 4; ++reg)
                A_b[(w * 16 + q * 4 + reg) * 136 + c] = f2b(acc[ct][reg] + bv);
        }
        __syncthreads();
        // coalesced bf16 stores: 64 rows x 128 cols
        u16* dst = xv_out + (size_t)row0 * F;
        #pragma unroll
        for (int i = 0; i < 8; ++i) {
            int idx = i * 256 + t, r = idx >> 5, seg = idx & 31;
            *(ushort4*)&dst[r * F + seg * 4] = *(const ushort4*)&A_b[r * 136 + seg * 4];
        }
    }
}

// ---------------------------------------------------------------------------
// attn v5: xj lives its WHOLE life in fp32 MFMA accumulator registers
// (C-layout: edge row = w*16 + q*4+reg, col ff = ct*16+m). The R0 version
// round-tripped xj through LDS as bf16 — ~800 VALU ops/thread of
// pack/unpack, which IS the measured 7000 CU-cycles/block (187us). Now:
//  - multiply: xv transposed via wave-private LDS rows (gather writer wave
//    == reader wave, no barrier), 32 scalar u16 reads, acc *= b2f(..)
//  - logits: reshape math: element (me,ff) contributes to
//    f = me*4 + (ff>>5), mm = ff&31  ->  per lane pE (mm=m) and pO (mm=16+m)
//    accumulate xi4[reg][j]*acc[2j(+1)][reg]; q-shuffle-reduce; tiny LDS
//  - combine: part[ct] = sum_reg att[me]*acc[ct][reg]; q-reduce; cross-wave
//    add via 2KB LDS; coalesced final store
// Per-thread VALU ~300 (was ~800); no pipeline reg state (R3/R4 spills);
// xj fp32 (was bf16-rounded) -> absmax can only improve.
// ---------------------------------------------------------------------------
__global__ __launch_bounds__(256, 4)
void attn_kernel(const float* __restrict__ xi_in, const u16* __restrict__ xvb,
                 const float* __restrict__ rbf, const int* __restrict__ idx_j,
                 const u16* __restrict__ k2fb, float* __restrict__ m_out)
{
    __shared__ u16   xv_s[64 * 136];     // 17408 B, row = block-edge
    __shared__ float slog[4][32];        // per-wave logit partials
    __shared__ float att_s[64];          // [node-local 2][32]
    __shared__ float comb[4][128];       // per-wave combine partials

    const int t = threadIdx.x, w = t >> 6, lane = t & 63;
    const int m = lane & 15, q = lane >> 4;
    const size_t e0 = (size_t)blockIdx.x * 64;
    const int n0 = blockIdx.x * 2;
    const int nw = n0 + (w >> 1);        // node this wave's edges belong to

    // ---- gather xv[idx_j] -> LDS rows (wave-private: writer wave == reader)
    {
        const int e_my = t >> 2, coff = (t & 3) * 32;
        const int jj = idx_j[e0 + e_my];
        const u16* xvp = xvb + (size_t)jj * F + coff;
        #pragma unroll
        for (int i = 0; i < 4; ++i)
            *(s8v*)&xv_s[e_my * 136 + coff + i * 8] = *(const s8v*)(xvp + i * 8);
    }

    // ---- g-GEMM: 16 edges/wave x 128 cols x K=64 -> acc (fp32, C-layout)
    f4v acc[8];
    #pragma unroll
    for (int ct = 0; ct < 8; ++ct) acc[ct] = (f4v){0.f, 0.f, 0.f, 0.f};
    {
        const float* arow = rbf + (e0 + (size_t)(w * 16 + m)) * KD;
        #pragma unroll
        for (int ks = 0; ks < 2; ++ks) {
            float4 a0 = *(const float4*)(arow + ks * 32 + q * 8);
            float4 a1 = *(const float4*)(arow + ks * 32 + q * 8 + 4);
            s8v a;
            a[0] = (short)f2b(a0.x); a[1] = (short)f2b(a0.y);
            a[2] = (short)f2b(a0.z); a[3] = (short)f2b(a0.w);
            a[4] = (short)f2b(a1.x); a[5] = (short)f2b(a1.y);
            a[6] = (short)f2b(a1.z); a[7] = (short)f2b(a1.w);
            #pragma unroll
            for (int ct = 0; ct < 8; ++ct) {
                s8v b = *(const s8v*)&k2fb[(ct * 16 + m) * KD + ks * 32 + q * 8];
                acc[ct] = __builtin_amdgcn_mfma_f32_16x16x32_bf16(a, b, acc[ct], 0, 0, 0);
            }
        }
    }

    // ---- xi fragments for logits: xi4[reg] = xi[nw][me(reg)*4 .. +3]
    // (loaded after the GEMM so GEMM-peak register pressure stays R0-level)
    float4 xi4[4];
    #pragma unroll
    for (int reg = 0; reg < 4; ++reg) {
        int me = (w & 1) * 16 + q * 4 + reg;
        xi4[reg] = *(const float4*)(xi_in + (size_t)nw * F + me * 4);
    }

    wfence();   // xv_s writes (this wave) -> reads below

    // ---- acc *= xv (transpose read from wave-private rows)
    #pragma unroll
    for (int ct = 0; ct < 8; ++ct) {
        int c = ct * 16 + m;
        #pragma unroll
        for (int reg = 0; reg < 4; ++reg)
            acc[ct][reg] *= b2f(xv_s[(w * 16 + q * 4 + reg) * 136 + c]);
    }

    // ---- logits in-register: pE -> logit[nw][m], pO -> logit[nw][16+m]
    float pE = 0.f, pO = 0.f;
    #pragma unroll
    for (int reg = 0; reg < 4; ++reg) {
        float xf[4] = {xi4[reg].x, xi4[reg].y, xi4[reg].z, xi4[reg].w};
        #pragma unroll
        for (int j = 0; j < 4; ++j) {
            pE = fmaf(xf[j], acc[2 * j][reg], pE);
            pO = fmaf(xf[j], acc[2 * j + 1][reg], pO);
        }
    }
    pE += __shfl_xor(pE, 16); pE += __shfl_xor(pE, 32);
    pO += __shfl_xor(pO, 16); pO += __shfl_xor(pO, 32);
    if (lane < 16) { slog[w][m] = pE; slog[w][16 + m] = pO; }
    __syncthreads();

    // ---- softmax (node nn's 32 logits = slog[2nn] + slog[2nn+1])
    if (t < 64) {
        const int nn = t >> 5, mm = t & 31;
        float s = slog[2 * nn][mm] + slog[2 * nn + 1][mm];
        float mx = s;
        #pragma unroll
        for (int o = 16; o; o >>= 1) mx = fmaxf(mx, __shfl_xor(mx, o));
        float ex = expf(s - mx);
        float sum = ex;
        #pragma unroll
        for (int o = 16; o; o >>= 1) sum += __shfl_xor(sum, o);
        att_s[nn * 32 + mm] = ex / sum;
    }
    __syncthreads();

    // ---- combine: part[ct] = sum_reg att[me(reg)] * acc[ct][reg]
    float part[8];
    {
        float av[4];
        #pragma unroll
        for (int reg = 0; reg < 4; ++reg)
            av[reg] = att_s[w * 16 + q * 4 + reg];   // broadcast across m-lanes
        #pragma unroll
        for (int ct = 0; ct < 8; ++ct) {
            float p = 0.f;
            #pragma unroll
            for (int reg = 0; reg < 4; ++reg) p = fmaf(av[reg], acc[ct][reg], p);
            p += __shfl_xor(p, 16); p += __shfl_xor(p, 32);
            part[ct] = p;
        }
    }
    if (lane < 16) {
        #pragma unroll
        for (int ct = 0; ct < 8; ++ct) comb[w][ct * 16 + m] = part[ct];
    }
    __syncthreads();

    // ---- final: m[n][f] = xi[n][f] + comb[2nn][f] + comb[2nn+1][f]
    {
        const int nn = t >> 7, f = t & 127;
        float v = xi_in[(size_t)(n0 + nn) * F + f]
                + comb[2 * nn][f] + comb[2 * nn + 1][f];
        m_out[(size_t)(n0 + nn) * F + f] = v;
    }
}

// ---------------------------------------------------------------------------
// tail (round-2 proven version): 32-row tiles, quadrant wave decomposition,
// grid 1024 = 4 blocks/CU.
// ---------------------------------------------------------------------------
__global__ __launch_bounds__(256, 4)
void tail_kernel(const float* __restrict__ m_in, const float* __restrict__ x,
                 const float* __restrict__ u, const u16* __restrict__ WB,
                 const float* __restrict__ rb1, const float* __restrict__ rb2,
                 const float* __restrict__ bd, float* __restrict__ out)
{
    __shared__ u16 A_b[32 * 136];
    const int t = threadIdx.x, row0 = blockIdx.x * 32;
    const int w = t >> 6, lane = t & 63, m = lane & 15, q = lane >> 4;
    const int rh = w & 1, cbase = (w >> 1) * 64;
    const int rbase = row0 + rh * 16 + q * 4;

    float cur[4][4], tmp[4][4];
    #pragma unroll
    for (int ct = 0; ct < 4; ++ct) {
        int c = cbase + ct * 16 + m;
        #pragma unroll
        for (int reg = 0; reg < 4; ++reg)
            cur[ct][reg] = m_in[(size_t)(rbase + reg) * F + c];
    }

    f4v acc[4];
    #pragma unroll 1
    for (int r = 0; r < 2; ++r) {
        #pragma unroll
        for (int ct = 0; ct < 4; ++ct)
            #pragma unroll
            for (int reg = 0; reg < 4; ++reg) tmp[ct][reg] = ssp(cur[ct][reg]);
        writeA32(A_b, rh, cbase, q, m, tmp);
        __syncthreads();
        mfma_gemm32(A_b, WB + (2 + 2 * r) * 16384, rh, cbase, m, q, acc);   // rw1_r
        __syncthreads();
        #pragma unroll
        for (int ct = 0; ct < 4; ++ct) {
            float bv = rb1[r * F + cbase + ct * 16 + m];
            #pragma unroll
            for (int reg = 0; reg < 4; ++reg) tmp[ct][reg] = acc[ct][reg] + bv;
        }
        writeA32(A_b, rh, cbase, q, m, tmp);
        __syncthreads();
        mfma_gemm32(A_b, WB + (3 + 2 * r) * 16384, rh, cbase, m, q, acc);   // rw2_r
        #pragma unroll
        for (int ct = 0; ct < 4; ++ct) {
            float bv = rb2[r * F + cbase + ct * 16 + m];
            #pragma unroll
            for (int reg = 0; reg < 4; ++reg) cur[ct][reg] += acc[ct][reg] + bv;
        }
        __syncthreads();
    }

    #pragma unroll
    for (int ct = 0; ct < 4; ++ct)
        #pragma unroll
        for (int reg = 0; reg < 4; ++reg) tmp[ct][reg] = ssp(cur[ct][reg]);
    writeA32(A_b, rh, cbase, q, m, tmp);
    __syncthreads();
    mfma_gemm32(A_b, WB + 6 * 16384, rh, cbase, m, q, acc);                 // wd
    #pragma unroll
    for (int ct = 0; ct < 4; ++ct) {
        int c = cbase + ct * 16 + m;
        float uv = u[c], bv = bd[c];
        #pragma unroll
        for (int reg = 0; reg < 4; ++reg) {
            size_t r = (size_t)(rbase + reg) * F + c;
            out[r] = fmaf(uv, x[r], acc[ct][reg] + bv);
        }
    }
}

// ---------------------------------------------------------------------------
extern "C" void kernel_launch(void* const* d_in, const int* in_sizes, int n_in,
                              void* d_out, int out_size, void* d_ws, size_t ws_size,
                              hipStream_t stream)
{
    const float* x     = (const float*)d_in[0];
    const float* rbf   = (const float*)d_in[1];
    const int*   idx_j = (const int*)d_in[3];   // idx_i (d_in[2]) unused by ref
    const float* k2f_w = (const float*)d_in[4];
    const float* wi    = (const float*)d_in[5];
    const float* bi    = (const float*)d_in[6];
    const float* wj    = (const float*)d_in[7];
    const float* bj    = (const float*)d_in[8];
    const float* rw1   = (const float*)d_in[9];
    const float* rb1   = (const float*)d_in[10];
    const float* rw2   = (const float*)d_in[11];
    const float* rb2   = (const float*)d_in[12];
    const float* wd    = (const float*)d_in[13];
    const float* bd    = (const float*)d_in[14];
    const float* u     = (const float*)d_in[15];
    float* out = (float*)d_out;

    const size_t NF = (size_t)N_NODES * F;
    float* B0   = (float*)d_ws;          // xi, then m (attn writes in place)
    u16*   XVB  = (u16*)(B0 + NF);       // xv bf16
    u16*   WB   = XVB + NF;              // 7 x [128][128] bf16 weights
    u16*   K2FB = WB + 7 * 16384;        // [128][64] bf16

    hipLaunchKernelGGL(prep_kernel, dim3(120), dim3(256), 0, stream,
                       wi, wj, rw1, rw2, wd, k2f_w, WB, K2FB);

    hipLaunchKernelGGL(in_kernel, dim3(1024), dim3(256), 0, stream,
                       x, WB, bi, bj, B0, XVB);

    hipLaunchKernelGGL(attn_kernel, dim3(N_NODES / 2), dim3(256), 0, stream,
                       B0, XVB, rbf, idx_j, K2FB, B0);

    hipLaunchKernelGGL(tail_kernel, dim3(1024), dim3(256), 0, stream,
                       B0, x, u, WB, rb1, rb2, bd, out);
}